// Round 4
// baseline (55.022 us; speedup 1.0000x reference)
//
#include <hip/hip_runtime.h>
#include <hip/hip_bf16.h>

namespace {

typedef __attribute__((ext_vector_type(8)))  short bf16x8;   // 8 bf16 = 4 VGPRs
typedef __attribute__((ext_vector_type(16))) float f32x16;   // MFMA 32x32 acc

constexpr int kB = 32, kT = 16384, kCin = 32, kCout = 32;
constexpr int kL = 64;             // owned rows per chunk
constexpr int kK = 32;             // zero-state warm-up (rho<~0.5 -> 0.5^32 ~ 2e-10)
constexpr int kChunks = kT / kL;   // 256

__device__ __forceinline__ short f2bf(float f) {
  return __builtin_bit_cast(short, __float2bfloat16(f));
}

// Wave = one (b, chunk). FIR via mfma_32x32x16_bf16 (A = u rows, B = taps),
// IIR runs directly on the accumulator layout with half-wave ping-pong.
// 8192 waves -> 32 waves/CU (full occupancy) to hide scattered-load latency.
__global__ __launch_bounds__(256, 8) void mimo_mfma(
    const float* __restrict__ u,        // [B, T, CIN]
    const float* __restrict__ x0,       // [B, 2, COUT]
    const float* __restrict__ a_coeff,  // [2, COUT]
    const float* __restrict__ b_coeff,  // [3, CIN, COUT]
    float* __restrict__ out)            // [B, T, COUT]
{
  const int lane = (int)threadIdx.x & 63;
  const int col  = lane & 31;          // output channel / A row index
  const int g    = lane >> 5;          // lane-group (k-slot group & C/D row +4)
  const int wid  = (int)blockIdx.x * 4 + ((int)threadIdx.x >> 6);
  const int b     = wid >> 8;          // 0..31  (wid / kChunks)
  const int chunk = wid & (kChunks - 1);
  const int t0     = chunk * kL;
  const int tstart = chunk ? (t0 - kK) : 0;
  const int ntiles = (t0 + kL - tstart) >> 5;   // 2 (chunk 0) or 3

  // B fragments: slot (g, j) of K-step (tau, h) holds b_coeff[2-tau][16h+8g+j][col].
  // A uses the SAME slot->k map, so the HW k-order cancels (bijection argument).
  bf16x8 Bf[3][2];
#pragma unroll
  for (int tau = 0; tau < 3; ++tau)
#pragma unroll
    for (int h = 0; h < 2; ++h) {
      const float* bp = b_coeff + (size_t)(2 - tau) * kCin * kCout
                        + (16 * h + 8 * g) * kCout + col;
      bf16x8 fr;
#pragma unroll
      for (int j = 0; j < 8; ++j) fr[j] = f2bf(bp[j * kCout]);
      Bf[tau][h] = fr;
    }

  const float a1 = a_coeff[col];          // * x[t-1]
  const float a2 = a_coeff[kCout + col];  // * x[t-2]
  float s1 = 0.f, s2 = 0.f;               // IIR state (x[t-1], x[t-2])
  if (chunk == 0) {
    s1 = x0[(b * 2 + 1) * kCout + col];
    s2 = x0[(b * 2 + 0) * kCout + col];
  }

  const float* ub = u + (size_t)b * kT * kCin;
  float* ob = out + (size_t)b * kT * kCout;

  for (int tile = 0; tile < ntiles; ++tile) {
    const int tbase = tstart + 32 * tile;

    // ---- FIR: v[32 x 32] = sum_{tau,h} u-rows(tbase-2+tau) x b_coeff ----
    f32x16 acc;
#pragma unroll
    for (int i = 0; i < 16; ++i) acc[i] = 0.f;

    const int arow = tbase + col - 2;   // this lane's A row, + tau
#pragma unroll
    for (int tau = 0; tau < 3; ++tau) {
      const int tr  = arow + tau;
      const int trc = tr < 0 ? 0 : tr;           // clamp; zeroed below
      const float* rp = ub + (size_t)trc * kCin + 8 * g;
#pragma unroll
      for (int h = 0; h < 2; ++h) {
        const float4 f0 = *(const float4*)(rp + 16 * h);
        const float4 f1 = *(const float4*)(rp + 16 * h + 4);
        float ff[8] = {f0.x, f0.y, f0.z, f0.w, f1.x, f1.y, f1.z, f1.w};
        bf16x8 fa;
#pragma unroll
        for (int j = 0; j < 8; ++j) {
          const float fv = (tr < 0) ? 0.f : ff[j];   // u[t<0] = 0 (chunk 0)
          fa[j] = f2bf(fv);
        }
        acc = __builtin_amdgcn_mfma_f32_32x32x16_bf16(fa, Bf[tau][h], acc, 0, 0, 0);
      }
    }

    // ---- IIR on acc: rows 4s..4s+3 live on half (s&1), regs 4*(s>>1)+q ----
    const bool owned = (tbase >= t0);
#pragma unroll
    for (int s = 0; s < 8; ++s) {
      const int q4 = 4 * (s >> 1);
      const float xv0 = fmaf(a1, s1,  fmaf(a2, s2,  acc[q4 + 0]));
      const float xv1 = fmaf(a1, xv0, fmaf(a2, s1,  acc[q4 + 1]));
      const float xv2 = fmaf(a1, xv1, fmaf(a2, xv0, acc[q4 + 2]));
      const float xv3 = fmaf(a1, xv2, fmaf(a2, xv1, acc[q4 + 3]));
      if (owned && g == (s & 1)) {
        float* op = ob + (size_t)(tbase + 4 * s) * kCout + col;
        op[0 * kCout] = xv0;
        op[1 * kCout] = xv1;
        op[2 * kCout] = xv2;
        op[3 * kCout] = xv3;
      }
      s1 = xv3; s2 = xv2;
      // pass state to the other half (valid half's values are the fresh ones)
      s1 = __shfl_xor(s1, 32);
      s2 = __shfl_xor(s2, 32);
    }
  }
}

}  // namespace

extern "C" void kernel_launch(void* const* d_in, const int* in_sizes, int n_in,
                              void* d_out, int out_size, void* d_ws, size_t ws_size,
                              hipStream_t stream) {
  const float* u  = (const float*)d_in[0];
  const float* x0 = (const float*)d_in[1];
  const float* a  = (const float*)d_in[2];
  const float* bb = (const float*)d_in[3];
  float* out = (float*)d_out;

  dim3 grid(kB * kChunks / 4);  // 8192 waves / 4 per block = 2048 blocks
  dim3 block(256);
  hipLaunchKernelGGL(mimo_mfma, grid, block, 0, stream, u, x0, a, bb, out);
}

// Round 5
// 29.772 us; speedup vs baseline: 1.8481x; 1.8481x over previous
//
#include <hip/hip_runtime.h>
#include <hip/hip_bf16.h>

namespace {

typedef __attribute__((ext_vector_type(8)))  short bf16x8;   // 8 bf16 = 4 VGPRs
typedef __attribute__((ext_vector_type(16))) float f32x16;   // MFMA 32x32 acc

constexpr int kB = 32, kT = 16384, kCin = 32, kCout = 32;
constexpr int kL = 128;            // owned rows per chunk (R3's winner)
constexpr int kK = 32;             // zero-state warm-up
constexpr int kChunks = kT / kL;   // 128
constexpr int kWpB = 4;            // waves per block
constexpr int kStageRows = 34;     // 32 rows + 2 halo rows

__device__ __forceinline__ short f2bf(float f) {
  return __builtin_bit_cast(short, __float2bfloat16(f));
}

// float4-index within a 34x32f stage -> XOR-swizzled LDS byte address.
// Swizzle spreads the 8 16B-slots of each 128B row across banks (T2).
__device__ __forceinline__ int swz(int f) {
  const int slot = f >> 3;          // row slot 0..33
  const int off  = (f & 7) << 4;    // byte offset in row
  return slot * 128 + (off ^ ((slot & 7) << 4));
}

// Wave = one (b, chunk). u staged coalesced -> wave-private swizzled LDS ->
// ds_read_b128 A-fragments -> mfma_32x32x16_bf16 FIR -> register IIR with
// one up-front full-acc half exchange (independent shuffles) + redundant chain.
__global__ __launch_bounds__(256, 4) void mimo_mfma2(
    const float* __restrict__ u,        // [B, T, CIN]
    const float* __restrict__ x0,       // [B, 2, COUT]
    const float* __restrict__ a_coeff,  // [2, COUT]
    const float* __restrict__ b_coeff,  // [3, CIN, COUT]
    float* __restrict__ out)            // [B, T, COUT]
{
  __shared__ float lds[kWpB][kStageRows * kCin];  // 4.25 KiB per wave

  const int tidx = (int)threadIdx.x;
  const int lane = tidx & 63;
  const int col  = lane & 31;          // output channel / A row offset
  const int g    = lane >> 5;          // lane-half
  const int widx = tidx >> 6;
  const int wid  = (int)blockIdx.x * kWpB + widx;
  const int b     = wid >> 7;          // 0..31
  const int chunk = wid & (kChunks - 1);
  const int t0     = chunk * kL;
  const int tstart = chunk ? (t0 - kK) : 0;
  const int ntiles = (t0 + kL - tstart) >> 5;   // 4 (chunk 0) or 5

  char* Lw = (char*)&lds[widx][0];

  // B fragments: slot (g, j) of K-step (tau, h) holds b_coeff[2-tau][16h+8g+j][col].
  // A uses the SAME slot->k map, so the HW k-order cancels (bijection argument).
  bf16x8 Bf[3][2];
#pragma unroll
  for (int tau = 0; tau < 3; ++tau)
#pragma unroll
    for (int h = 0; h < 2; ++h) {
      const float* bp = b_coeff + (size_t)(2 - tau) * kCin * kCout
                        + (16 * h + 8 * g) * kCout + col;
      bf16x8 fr;
#pragma unroll
      for (int j = 0; j < 8; ++j) fr[j] = f2bf(bp[j * kCout]);
      Bf[tau][h] = fr;
    }

  const float a1 = a_coeff[col];
  const float a2 = a_coeff[kCout + col];
  float s1 = 0.f, s2 = 0.f;
  if (chunk == 0) {
    s1 = x0[(b * 2 + 1) * kCout + col];
    s2 = x0[(b * 2 + 0) * kCout + col];
  }

  const float* ub = u + (size_t)b * kT * kCin;
  float* ob = out + (size_t)b * kT * kCout;

  // Coalesced stage load: f4-index f of a 34-row stage whose first row is rowbase.
  auto gload = [&](int rowbase, int f) -> float4 {
    const int grow = rowbase + (f >> 3);
    if (grow >= 0)
      return *(const float4*)(ub + (size_t)grow * kCin + ((f & 7) << 2));
    float4 z; z.x = 0.f; z.y = 0.f; z.z = 0.f; z.w = 0.f;
    return z;
  };

  // ds_read base addr per tau (loop-invariant): row slot = col+tau,
  // byte off = (32g + 64h + 16sec) ^ ((slot&7)<<4); bits of 32g/64h/16sec are
  // disjoint, so addr = LB[tau] ^ (64h + 16sec).
  int LB[3];
#pragma unroll
  for (int tau = 0; tau < 3; ++tau) {
    const int slot = col + tau;
    LB[tau] = slot * 128 + ((32 * g) ^ ((slot & 7) << 4));
  }

  // -------- prologue: stage rows [tstart-2, tstart+32) --------
  {
    const int rowbase = tstart - 2;   // rows < 0 (chunk 0) staged as zeros
    float4 p0 = gload(rowbase, lane);
    float4 p1 = gload(rowbase, lane + 64);
    float4 p2 = gload(rowbase, lane + 128);
    float4 p3 = gload(rowbase, lane + 192);
    *(float4*)(Lw + swz(lane))       = p0;
    *(float4*)(Lw + swz(lane + 64))  = p1;
    *(float4*)(Lw + swz(lane + 128)) = p2;
    *(float4*)(Lw + swz(lane + 192)) = p3;
    if (lane < 16) *(float4*)(Lw + swz(lane + 256)) = gload(rowbase, lane + 256);
  }

  for (int tile = 0; tile < ntiles; ++tile) {
    const int tbase = tstart + 32 * tile;
    const bool last = (tile + 1 == ntiles);

    // T14 issue-early: next stage's coalesced global loads fly during compute.
    float4 n0, n1, n2, n3, n4;
    if (!last) {
      const int rowbase = tbase + 30;   // (tbase+32) - 2
      n0 = gload(rowbase, lane);
      n1 = gload(rowbase, lane + 64);
      n2 = gload(rowbase, lane + 128);
      n3 = gload(rowbase, lane + 192);
      if (lane < 16) n4 = gload(rowbase, lane + 256);
    }

    // ---- FIR: A-fragments via swizzled ds_read_b128, 6 MFMAs ----
    f32x16 acc;
#pragma unroll
    for (int i = 0; i < 16; ++i) acc[i] = 0.f;
#pragma unroll
    for (int tau = 0; tau < 3; ++tau) {
#pragma unroll
      for (int h = 0; h < 2; ++h) {
        const float4 r0 = *(const float4*)(Lw + (LB[tau] ^ (64 * h)));
        const float4 r1 = *(const float4*)(Lw + (LB[tau] ^ (64 * h + 16)));
        bf16x8 fa;
        fa[0] = f2bf(r0.x); fa[1] = f2bf(r0.y); fa[2] = f2bf(r0.z); fa[3] = f2bf(r0.w);
        fa[4] = f2bf(r1.x); fa[5] = f2bf(r1.y); fa[6] = f2bf(r1.z); fa[7] = f2bf(r1.w);
        acc = __builtin_amdgcn_mfma_f32_32x32x16_bf16(fa, Bf[tau][h], acc, 0, 0, 0);
      }
    }

    // ---- full-acc half exchange: 16 INDEPENDENT shuffles (pipelined) ----
    float oth[16];
#pragma unroll
    for (int i = 0; i < 16; ++i) oth[i] = __shfl_xor(acc[i], 32);

    // ---- IIR: both halves run the identical 32-step chain redundantly ----
    // C/D layout: reg r (lane-half g) holds row (r&3) + 8*(r>>2) + 4g.
    const bool owned = (tbase >= t0);
    float x1 = s1, x2 = s2;
#pragma unroll
    for (int j = 0; j < 32; ++j) {
      const int reg = 4 * (j >> 3) + (j & 3);
      const int g4  = (j >> 2) & 1;
      const float v = (g4 == g) ? acc[reg] : oth[reg];
      const float xn = fmaf(a1, x1, fmaf(a2, x2, v));
      if (owned && g4 == g) ob[(size_t)(tbase + j) * kCout + col] = xn;
      x2 = x1; x1 = xn;
    }
    s1 = x1; s2 = x2;

    // write-late: refill the (single) stage buffer. Wave-local DS ops are
    // in-order, and the writes alias the reads so the compiler keeps order.
    if (!last) {
      *(float4*)(Lw + swz(lane))       = n0;
      *(float4*)(Lw + swz(lane + 64))  = n1;
      *(float4*)(Lw + swz(lane + 128)) = n2;
      *(float4*)(Lw + swz(lane + 192)) = n3;
      if (lane < 16) *(float4*)(Lw + swz(lane + 256)) = n4;
    }
  }
}

}  // namespace

extern "C" void kernel_launch(void* const* d_in, const int* in_sizes, int n_in,
                              void* d_out, int out_size, void* d_ws, size_t ws_size,
                              hipStream_t stream) {
  const float* u  = (const float*)d_in[0];
  const float* x0 = (const float*)d_in[1];
  const float* a  = (const float*)d_in[2];
  const float* bb = (const float*)d_in[3];
  float* out = (float*)d_out;

  dim3 grid(kB * kChunks / kWpB);  // 4096 waves / 4 = 1024 blocks
  dim3 block(256);
  hipLaunchKernelGGL(mimo_mfma2, grid, block, 0, stream, u, x0, a, bb, out);
}